// Round 6
// baseline (613.202 us; speedup 1.0000x reference)
//
#include <hip/hip_runtime.h>

typedef unsigned int u32;
typedef unsigned short u16;
typedef __attribute__((ext_vector_type(8))) short short8;
typedef __attribute__((ext_vector_type(16))) float f32x16;

// Problem constants
#define NA   50000      // atoms
#define MN   12         // neighbors
#define FD   128        // atom feature len
#define KD   64         // nbr feature len
#define NMR  600000     // NA*MN edge rows
#define KIN  320        // 2F+K
#define NT   18750      // NMR/32 row tiles
#define NBLK 1024       // persistent blocks for pass A/B (4 per CU)
#define NBLK3 256       // k3s stat blocks
#define BN_EPS 1e-5f
#define LOG2E 1.4426950408889634f
#define LN2   0.6931471805599453f

// ---- fast transcendentals ----
#if __has_builtin(__builtin_amdgcn_exp2f)
#define EXP2F(x) __builtin_amdgcn_exp2f(x)
#else
#define EXP2F(x) exp2f(x)
#endif
#if __has_builtin(__builtin_amdgcn_logf)
#define LOG2F(x) __builtin_amdgcn_logf(x)
#else
#define LOG2F(x) log2f(x)
#endif
#if __has_builtin(__builtin_amdgcn_rcpf)
#define RCPF(x) __builtin_amdgcn_rcpf(x)
#else
#define RCPF(x) (1.f / (x))
#endif

__device__ __forceinline__ float fast_sigmoid(float x) {
    return RCPF(1.f + EXP2F(-x * LOG2E));
}
__device__ __forceinline__ float fast_softplus(float x) {
    float e = EXP2F(-fabsf(x) * LOG2E);
    return fmaxf(x, 0.f) + LN2 * LOG2F(1.f + e);
}

// ---- manual bf16 (RNE) helpers ----
__device__ __forceinline__ u32 f2bf_bits(float f) {
    u32 u = __float_as_uint(f);
    return u + 0x7fffu + ((u >> 16) & 1u);
}
__device__ __forceinline__ u32 pack2(float lo, float hi) {
    return (f2bf_bits(lo) >> 16) | (f2bf_bits(hi) & 0xffff0000u);
}
__device__ __forceinline__ float bflo(u32 u) { return __uint_as_float(u << 16); }
__device__ __forceinline__ float bfhi(u32 u) { return __uint_as_float(u & 0xffff0000u); }
__device__ __forceinline__ short8 pack8(float4 x, float4 y) {
    union { short8 s; uint4 u; } cv;
    cv.u = make_uint4(pack2(x.x, x.y), pack2(x.z, x.w),
                      pack2(y.x, y.y), pack2(y.z, y.w));
    return cv.s;
}

// ---------------------------------------------------------------------------
// K0: pre-pack W into MFMA B-fragment order (coalesced 16B/lane loads later).
// wf12: ((h*8+ct)*8+s)*64+L, j=ct*32+(L&31), k=h*128+s*16+(L>>5)*8  (128 KB)
// wf3 : (ct*4+s)*64+L,       j=ct*32+(L&31), k=256+s*16+(L>>5)*8    (32 KB)
// ---------------------------------------------------------------------------
__global__ __launch_bounds__(256) void k0_wfrag(const float* __restrict__ W,
                                                u16* __restrict__ wf12,
                                                u16* __restrict__ wf3) {
    const int tid = blockIdx.x * 256 + threadIdx.x;
    int j, k;
    short8* dst;
    if (tid < 8192) {
        const int e  = tid;
        const int L  = e & 63;
        const int s  = (e >> 6) & 7;
        const int ct = (e >> 9) & 7;
        const int h  = e >> 12;
        j = ct * 32 + (L & 31);
        k = h * 128 + s * 16 + (L >> 5) * 8;
        dst = (short8*)wf12 + e;
    } else {
        const int e  = tid - 8192;
        const int L  = e & 63;
        const int s  = (e >> 6) & 3;
        const int ct = e >> 8;
        j = ct * 32 + (L & 31);
        k = 256 + s * 16 + (L >> 5) * 8;
        dst = (short8*)wf3 + e;
    }
    const float* wr = &W[(size_t)j * KIN + k];
    float4 x = *(const float4*)&wr[0];
    float4 y = *(const float4*)&wr[4];
    *dst = pack8(x, y);
}

// ---------------------------------------------------------------------------
// K1 (MFMA): P12 interleaved bf16: u32 word at p12[r*256 + h*128 + c] holds
// (filter j=c [low], core j=c+128 [high]) of P_h. Bias skipped (cancels
// through BN1 mean). B-frags from wf12 (coalesced); stores coalesced u32.
// Block = 64 rows; wave w: rows 32*(w&1), half h=w>>1 (P1/P2).
// ---------------------------------------------------------------------------
__global__ __launch_bounds__(256, 3) void k1_p12(const float* __restrict__ atom,
                                                 const u16* __restrict__ wf12,
                                                 u32* __restrict__ p12) {
    const int t  = threadIdx.x;
    const int w  = t >> 6;
    const int L  = t & 63;
    const int rg = w & 1, h = w >> 1;
    const int lr = L & 31, lk = L >> 5;
    const int r0 = blockIdx.x * 64 + rg * 32;

    int row = r0 + lr; if (row > NA - 1) row = NA - 1;
    const float* ar = &atom[(size_t)row * FD + lk * 8];
    short8 af[8];
#pragma unroll
    for (int s = 0; s < 8; s++) {
        float4 x = *(const float4*)&ar[s * 16];
        float4 y = *(const float4*)&ar[s * 16 + 4];
        af[s] = pack8(x, y);
    }
    const short8* wf = (const short8*)wf12;
#pragma unroll
    for (int cp = 0; cp < 4; cp++) {
        f32x16 accf, accc;
#pragma unroll
        for (int p = 0; p < 16; p++) { accf[p] = 0.f; accc[p] = 0.f; }
        {
            short8 bf[8];
#pragma unroll
            for (int s = 0; s < 8; s++) bf[s] = wf[((h * 8 + cp) * 8 + s) * 64 + L];
#pragma unroll
            for (int s = 0; s < 8; s++)
                accf = __builtin_amdgcn_mfma_f32_32x32x16_bf16(af[s], bf[s], accf, 0, 0, 0);
        }
        {
            short8 bf[8];
#pragma unroll
            for (int s = 0; s < 8; s++) bf[s] = wf[((h * 8 + cp + 4) * 8 + s) * 64 + L];
#pragma unroll
            for (int s = 0; s < 8; s++)
                accc = __builtin_amdgcn_mfma_f32_32x32x16_bf16(af[s], bf[s], accc, 0, 0, 0);
        }
#pragma unroll
        for (int p = 0; p < 16; p++) {
            const int r = r0 + (p & 3) + 8 * (p >> 2) + 4 * lk;
            if (r < NA)
                p12[(size_t)r * 256 + h * 128 + cp * 32 + lr] = pack2(accf[p], accc[p]);
        }
    }
}

// ---------------------------------------------------------------------------
// Pass A (k2s): LDS-free, barrier-free. 32-row tiles; wave w owns paired cols
// (w*32+lr, 128+w*32+lr) -> filter/core pairing is element-wise between the
// two accumulators (lane = column). Per-col BN1 stats in 4 registers,
// combined across row-halves with one shfl_xor at the end.
// ---------------------------------------------------------------------------
__global__ __launch_bounds__(256, 3) void k2s(const float* __restrict__ nbr,
                                              const int* __restrict__ nidx,
                                              const u16* __restrict__ wf3,
                                              const u32* __restrict__ p12,
                                              float* __restrict__ partial1) {
    const int t  = threadIdx.x;
    const int w  = t >> 6;
    const int L  = t & 63;
    const int lr = L & 31, lk = L >> 5;
    const int cf = w * 32 + lr;          // filter col; core col = 128+cf

    const short8* wf = (const short8*)wf3;
    short8 bf_f[4], bf_c[4];
#pragma unroll
    for (int s = 0; s < 4; s++) {
        bf_f[s] = wf[(w * 4 + s) * 64 + L];
        bf_c[s] = wf[((w + 4) * 4 + s) * 64 + L];
    }
    float sf = 0.f, qf = 0.f, sc = 0.f, qc = 0.f;

    for (int tile = blockIdx.x; tile < NT; tile += NBLK) {
        const int g0 = tile * 32;
        const float* ar = &nbr[(size_t)(g0 + lr) * KD + lk * 8];
        short8 af[4];
#pragma unroll
        for (int s = 0; s < 4; s++) {
            float4 x = *(const float4*)&ar[s * 16];
            float4 y = *(const float4*)&ar[s * 16 + 4];
            af[s] = pack8(x, y);
        }
        f32x16 accf, accc;
#pragma unroll
        for (int p = 0; p < 16; p++) { accf[p] = 0.f; accc[p] = 0.f; }
#pragma unroll
        for (int s = 0; s < 4; s++) {
            accf = __builtin_amdgcn_mfma_f32_32x32x16_bf16(af[s], bf_f[s], accf, 0, 0, 0);
            accc = __builtin_amdgcn_mfma_f32_32x32x16_bf16(af[s], bf_c[s], accc, 0, 0, 0);
        }
#pragma unroll
        for (int p = 0; p < 16; p++) {
            const int row = (p & 3) + 8 * (p >> 2) + 4 * lk;
            const int g   = g0 + row;
            const u32 n   = (u32)g / 12u;
            const int iv  = nidx[g];
            const float mk = (iv != 0) ? 1.f : 0.f;
            const u32 U1 = p12[n * 256u + cf];
            const u32 U2 = p12[(u32)iv * 256u + 128u + cf];
            float vf = bflo(U1) + mk * (bflo(U2) + accf[p]);
            float vc = bfhi(U1) + mk * (bfhi(U2) + accc[p]);
            sf += vf; qf += vf * vf;
            sc += vc; qc += vc * vc;
        }
    }
    sf += __shfl_xor(sf, 32); qf += __shfl_xor(qf, 32);
    sc += __shfl_xor(sc, 32); qc += __shfl_xor(qc, 32);
    if (L < 32) {
        float* pb = &partial1[(size_t)blockIdx.x * 512];
        pb[cf]       = sf;   // sum, filter col cf
        pb[128 + cf] = sc;   // sum, core col 128+cf
        pb[256 + cf] = qf;   // sumsq, filter
        pb[384 + cf] = qc;   // sumsq, core
    }
}

// ---------------------------------------------------------------------------
// K2b: finalize BN1 -> bn1[c]=scale, bn1[256+c]=shift
// ---------------------------------------------------------------------------
__global__ __launch_bounds__(64) void k2b_bn1(const float* __restrict__ partial1,
                                              const float* __restrict__ gamma1,
                                              const float* __restrict__ beta1,
                                              float* __restrict__ bn1) {
    const int c = blockIdx.x;
    const int t = threadIdx.x;
    double s = 0.0, q = 0.0;
    for (int b = t; b < NBLK; b += 64) {
        s += (double)partial1[(size_t)b * 512 + c];
        q += (double)partial1[(size_t)b * 512 + 256 + c];
    }
#pragma unroll
    for (int off = 32; off > 0; off >>= 1) {
        s += __shfl_down(s, off);
        q += __shfl_down(q, off);
    }
    if (t == 0) {
        double mean = s / (double)NMR;
        double var  = q / (double)NMR - mean * mean;
        float scale = gamma1[c] * rsqrtf((float)var + BN_EPS);
        bn1[c]       = scale;
        bn1[256 + c] = fmaf(-(float)mean, scale, beta1[c]);
    }
}

// ---------------------------------------------------------------------------
// Pass B (k3r): recompute Q (identical MFMA chain), in-register activation,
// per-atom predicated row sums (rows ascend with p; <=4 atoms per 32-row
// tile), shfl-combine halves, one atomicAdd per (atom, col).
// ---------------------------------------------------------------------------
__global__ __launch_bounds__(256, 3) void k3r(const float* __restrict__ nbr,
                                              const int* __restrict__ nidx,
                                              const u16* __restrict__ wf3,
                                              const u32* __restrict__ p12,
                                              const float* __restrict__ bn1,
                                              float* __restrict__ nsum) {
    const int t  = threadIdx.x;
    const int w  = t >> 6;
    const int L  = t & 63;
    const int lr = L & 31, lk = L >> 5;
    const int cf = w * 32 + lr;

    const short8* wf = (const short8*)wf3;
    short8 bf_f[4], bf_c[4];
#pragma unroll
    for (int s = 0; s < 4; s++) {
        bf_f[s] = wf[(w * 4 + s) * 64 + L];
        bf_c[s] = wf[((w + 4) * 4 + s) * 64 + L];
    }
    const float scf = bn1[cf],       shf = bn1[256 + cf];
    const float scc = bn1[128 + cf], shc = bn1[384 + cf];

    for (int tile = blockIdx.x; tile < NT; tile += NBLK) {
        const int g0 = tile * 32;
        const float* ar = &nbr[(size_t)(g0 + lr) * KD + lk * 8];
        short8 af[4];
#pragma unroll
        for (int s = 0; s < 4; s++) {
            float4 x = *(const float4*)&ar[s * 16];
            float4 y = *(const float4*)&ar[s * 16 + 4];
            af[s] = pack8(x, y);
        }
        f32x16 accf, accc;
#pragma unroll
        for (int p = 0; p < 16; p++) { accf[p] = 0.f; accc[p] = 0.f; }
#pragma unroll
        for (int s = 0; s < 4; s++) {
            accf = __builtin_amdgcn_mfma_f32_32x32x16_bf16(af[s], bf_f[s], accf, 0, 0, 0);
            accc = __builtin_amdgcn_mfma_f32_32x32x16_bf16(af[s], bf_c[s], accc, 0, 0, 0);
        }
        const int a0  = g0 / 12;
        const int rl0 = a0 * 12 - g0;     // in {-8,-4,0}
        float asum[4] = {0.f, 0.f, 0.f, 0.f};
#pragma unroll
        for (int p = 0; p < 16; p++) {
            const int row = (p & 3) + 8 * (p >> 2) + 4 * lk;
            const int g   = g0 + row;
            const u32 n   = (u32)g / 12u;
            const int iv  = nidx[g];
            const float mk = (iv != 0) ? 1.f : 0.f;
            const u32 U1 = p12[n * 256u + cf];
            const u32 U2 = p12[(u32)iv * 256u + 128u + cf];
            float gf = bflo(U1) + mk * (bflo(U2) + accf[p]);
            float gc = bfhi(U1) + mk * (bfhi(U2) + accc[p]);
            float act = fast_sigmoid(fmaf(gf, scf, shf)) *
                        fast_softplus(fmaf(gc, scc, shc)) * mk;
#pragma unroll
            for (int a = 0; a < 4; a++) {
                const int d = row - (rl0 + a * 12);
                asum[a] += (d >= 0 && d < 12) ? act : 0.f;
            }
        }
#pragma unroll
        for (int a = 0; a < 4; a++) {
            float v = asum[a] + __shfl_xor(asum[a], 32);
            if (L < 32 && (rl0 + a * 12) < 32)
                atomicAdd(&nsum[(size_t)(a0 + a) * 128 + cf], v);
        }
    }
}

// ---------------------------------------------------------------------------
// K3s: BN2 stats sweep over completed nsum -> partial2[block][256]
// ---------------------------------------------------------------------------
__global__ __launch_bounds__(256) void k3s(const float* __restrict__ nsum,
                                           float* __restrict__ partial2) {
    __shared__ float red[512];
    const int t  = threadIdx.x;
    const int c  = t & 127;
    const int rs = t >> 7;
    float s = 0.f, q = 0.f;
    for (int n = blockIdx.x * 2 + rs; n < NA; n += NBLK3 * 2) {
        float v = nsum[(size_t)n * 128 + c];
        s += v; q += v * v;
    }
    red[t] = s; red[256 + t] = q;
    __syncthreads();
    if (t < 128) {
        partial2[(size_t)blockIdx.x * 256 + t]       = red[t] + red[128 + t];
        partial2[(size_t)blockIdx.x * 256 + 128 + t] = red[256 + t] + red[384 + t];
    }
}

// ---------------------------------------------------------------------------
// K3b: finalize BN2 -> bn2[c]=scale, bn2[128+c]=shift
// ---------------------------------------------------------------------------
__global__ __launch_bounds__(64) void k3b_bn2(const float* __restrict__ partial2,
                                              const float* __restrict__ gamma2,
                                              const float* __restrict__ beta2,
                                              float* __restrict__ bn2) {
    const int c = blockIdx.x;
    const int t = threadIdx.x;
    double s = 0.0, q = 0.0;
    for (int b = t; b < NBLK3; b += 64) {
        s += (double)partial2[(size_t)b * 256 + c];
        q += (double)partial2[(size_t)b * 256 + 128 + c];
    }
#pragma unroll
    for (int off = 32; off > 0; off >>= 1) {
        s += __shfl_down(s, off);
        q += __shfl_down(q, off);
    }
    if (t == 0) {
        double mean = s / (double)NA;
        double var  = q / (double)NA - mean * mean;
        float scale = gamma2[c] * rsqrtf((float)var + BN_EPS);
        bn2[c]       = scale;
        bn2[128 + c] = fmaf(-(float)mean, scale, beta2[c]);
    }
}

// ---------------------------------------------------------------------------
// K4: out = softplus(atom_in + nbr_sumed*scale2 + shift2)
// ---------------------------------------------------------------------------
__global__ __launch_bounds__(256) void k4_out(const float* __restrict__ atom,
                                              const float* __restrict__ nsum,
                                              const float* __restrict__ bn2,
                                              float* __restrict__ out) {
    const int i  = blockIdx.x * 256 + threadIdx.x;   // float4 index, 1.6M exact
    const int c0 = (i & 31) * 4;
    float4 a = ((const float4*)atom)[i];
    float4 s = ((const float4*)nsum)[i];
    float4 r;
    r.x = fast_softplus(a.x + fmaf(s.x, bn2[c0 + 0], bn2[128 + c0 + 0]));
    r.y = fast_softplus(a.y + fmaf(s.y, bn2[c0 + 1], bn2[128 + c0 + 1]));
    r.z = fast_softplus(a.z + fmaf(s.z, bn2[c0 + 2], bn2[128 + c0 + 2]));
    r.w = fast_softplus(a.w + fmaf(s.w, bn2[c0 + 3], bn2[128 + c0 + 3]));
    ((float4*)out)[i] = r;
}

// ---------------------------------------------------------------------------
extern "C" void kernel_launch(void* const* d_in, const int* in_sizes, int n_in,
                              void* d_out, int out_size, void* d_ws, size_t ws_size,
                              hipStream_t stream) {
    const float* atom   = (const float*)d_in[0];
    const float* nbr    = (const float*)d_in[1];
    const int*   nidx   = (const int*)d_in[2];
    const float* W      = (const float*)d_in[3];
    // d_in[4] = b : unused — cancels exactly through BN1 mean subtraction
    const float* gamma1 = (const float*)d_in[5];
    const float* beta1  = (const float*)d_in[6];
    const float* gamma2 = (const float*)d_in[7];
    const float* beta2  = (const float*)d_in[8];
    float* out = (float*)d_out;

    // ws layout: wf12 128KB | wf3 32KB | p12 51.2MB | nsum 25.6MB | partials
    u16* wf12 = (u16*)d_ws;
    u16* wf3  = wf12 + 8192 * 8;
    u32* p12  = (u32*)(wf3 + 2048 * 8);
    float* nsum     = (float*)(p12 + (size_t)NA * 256);
    float* partial1 = nsum + (size_t)NA * 128;
    float* partial2 = partial1 + (size_t)NBLK * 512;
    float* bn1      = partial2 + (size_t)NBLK3 * 256;
    float* bn2      = bn1 + 512;

    hipMemsetAsync(nsum, 0, (size_t)NA * 128 * sizeof(float), stream);
    k0_wfrag<<<40,    256, 0, stream>>>(W, wf12, wf3);
    k1_p12 <<<782,   256, 0, stream>>>(atom, wf12, p12);
    k2s    <<<NBLK,  256, 0, stream>>>(nbr, nidx, wf3, p12, partial1);
    k2b_bn1<<<256,    64, 0, stream>>>(partial1, gamma1, beta1, bn1);
    k3r    <<<NBLK,  256, 0, stream>>>(nbr, nidx, wf3, p12, bn1, nsum);
    k3s    <<<NBLK3, 256, 0, stream>>>(nsum, partial2);
    k3b_bn2<<<128,    64, 0, stream>>>(partial2, gamma2, beta2, bn2);
    k4_out <<<6250,  256, 0, stream>>>(atom, nsum, bn2, out);
}